// Round 1
// baseline (807.710 us; speedup 1.0000x reference)
//
#include <hip/hip_runtime.h>
#include <hip/hip_bf16.h>

#define D_DIM 1024
#define H_DIM 4096
#define E_NUM 8
#define T_TOK 8192
#define CAPN 2252
#define CAP_PAD 2304   // 18 * 128
#define MT 18

typedef __attribute__((ext_vector_type(8))) short short8;
typedef __attribute__((ext_vector_type(4))) float f32x4;
typedef const __attribute__((address_space(1))) void* gas_ptr;
typedef __attribute__((address_space(3))) void* las_ptr;

__device__ __forceinline__ unsigned short f2bf(float f) {
    __hip_bfloat16 h = __float2bfloat16(f);
    return __builtin_bit_cast(unsigned short, h);
}

// ---------------- Router: logits, noisy top-2, gates; fuses x -> bf16 ----------------
__global__ void router_kernel(const float* __restrict__ x,
                              const float* __restrict__ noise,
                              const float* __restrict__ Wr,
                              const float* __restrict__ br,
                              const float* __restrict__ Wn,
                              const float* __restrict__ bn,
                              __hip_bfloat16* __restrict__ xb,
                              int* __restrict__ tok_e,
                              float* __restrict__ tok_g)
{
    const int l = threadIdx.x & 63;
    const int w = threadIdx.x >> 6;
    const int t = blockIdx.x * 4 + w;
    const float* xr = x + (size_t)t * D_DIM;

    float ar[8] = {0,0,0,0,0,0,0,0};
    float an[8] = {0,0,0,0,0,0,0,0};
#pragma unroll
    for (int i = 0; i < 4; ++i) {
        int d = i * 256 + l * 4;
        float4 xv = *(const float4*)(xr + d);
        ushort4 xq;
        xq.x = f2bf(xv.x); xq.y = f2bf(xv.y); xq.z = f2bf(xv.z); xq.w = f2bf(xv.w);
        *(ushort4*)(xb + (size_t)t * D_DIM + d) = xq;
        float xs[4] = {xv.x, xv.y, xv.z, xv.w};
#pragma unroll
        for (int j = 0; j < 4; ++j) {
            const float* wrp = Wr + (size_t)(d + j) * 8;
            float4 wa = *(const float4*)wrp;
            float4 wb = *(const float4*)(wrp + 4);
            ar[0] = fmaf(xs[j], wa.x, ar[0]); ar[1] = fmaf(xs[j], wa.y, ar[1]);
            ar[2] = fmaf(xs[j], wa.z, ar[2]); ar[3] = fmaf(xs[j], wa.w, ar[3]);
            ar[4] = fmaf(xs[j], wb.x, ar[4]); ar[5] = fmaf(xs[j], wb.y, ar[5]);
            ar[6] = fmaf(xs[j], wb.z, ar[6]); ar[7] = fmaf(xs[j], wb.w, ar[7]);
            const float* wnp = Wn + (size_t)(d + j) * 8;
            float4 na = *(const float4*)wnp;
            float4 nb = *(const float4*)(wnp + 4);
            an[0] = fmaf(xs[j], na.x, an[0]); an[1] = fmaf(xs[j], na.y, an[1]);
            an[2] = fmaf(xs[j], na.z, an[2]); an[3] = fmaf(xs[j], na.w, an[3]);
            an[4] = fmaf(xs[j], nb.x, an[4]); an[5] = fmaf(xs[j], nb.y, an[5]);
            an[6] = fmaf(xs[j], nb.z, an[6]); an[7] = fmaf(xs[j], nb.w, an[7]);
        }
    }
#pragma unroll
    for (int e = 0; e < 8; ++e) {
#pragma unroll
        for (int s = 32; s > 0; s >>= 1) {
            ar[e] += __shfl_xor(ar[e], s, 64);
            an[e] += __shfl_xor(an[e], s, 64);
        }
    }
    if (l == 0) {
        float nv[8];
#pragma unroll
        for (int e = 0; e < 8; ++e) {
            float z = an[e] + bn[e];
            float sp = fmaxf(z, 0.f) + log1pf(expf(-fabsf(z)));   // softplus, stable
            nv[e] = ar[e] + br[e] + noise[(size_t)t * 8 + e] * sp;
        }
        int e0 = 0; float v0 = nv[0];
#pragma unroll
        for (int e = 1; e < 8; ++e) if (nv[e] > v0) { v0 = nv[e]; e0 = e; }  // ties -> lower idx
        int e1 = -1; float v1 = -3.4e38f;
#pragma unroll
        for (int e = 0; e < 8; ++e) if (e != e0 && nv[e] > v1) { v1 = nv[e]; e1 = e; }
        float ex = expf(v1 - v0);          // v1 <= v0, no overflow
        float p0 = 1.f / (1.f + ex);
        float p1 = ex * p0;
        tok_e[2 * t]     = e0; tok_e[2 * t + 1] = e1;
        tok_g[2 * t]     = p0; tok_g[2 * t + 1] = p1;
    }
}

// ---------- Capacity scan: wave e compacts its tokens in order; lb_loss sums ----------
__global__ void scan_kernel(const int* __restrict__ tok_e,
                            const float* __restrict__ tok_g,
                            int* __restrict__ routed,
                            int* __restrict__ inv,
                            int* __restrict__ nkept,
                            float* __restrict__ lb_out)
{
    const int e = threadIdx.x >> 6;
    const int l = threadIdx.x & 63;
    __shared__ float s_g[E_NUM];
    __shared__ int   s_c[E_NUM];

    int run = 0;
    float gsum = 0.f;
    for (int c = 0; c < T_TOK / 64; ++c) {
        int t = c * 64 + l;
        int e0 = tok_e[2 * t];
        int e1 = tok_e[2 * t + 1];
        int j = (e0 == e) ? 0 : ((e1 == e) ? 1 : -1);
        bool sel = (j >= 0);
        unsigned long long m = __ballot(sel);
        if (sel) {
            int pos = run + __popcll(m & ((1ull << l) - 1ull));
            if (pos < CAPN) {
                routed[e * CAP_PAD + pos] = t;
                inv[2 * t + j] = e * CAP_PAD + pos;
            }
            gsum += tok_g[2 * t + j];     // pre-capacity, matches reference lb
        }
        run += __popcll(m);
    }
#pragma unroll
    for (int s = 32; s > 0; s >>= 1) gsum += __shfl_xor(gsum, s, 64);
    int nk = min(run, CAPN);
    for (int s = nk + l; s < CAP_PAD; s += 64) routed[e * CAP_PAD + s] = 0;  // safe pad
    if (l == 0) { nkept[e] = nk; s_g[e] = gsum; s_c[e] = run; }
    __syncthreads();
    if (threadIdx.x == 0) {
        float lb = 0.f;
        for (int ee = 0; ee < E_NUM; ++ee)
            lb += (s_g[ee] / (float)T_TOK) * ((float)s_c[ee] / (float)T_TOK);
        lb_out[0] = lb * (float)E_NUM;
    }
}

// -------- Transpose + f32->bf16: in [E][R][C] f32  ->  out [E][C][R] bf16 --------
__global__ void transpose_kernel(const float* __restrict__ in,
                                 __hip_bfloat16* __restrict__ out,
                                 int R, int C)
{
    __shared__ float tile[64][65];
    const int e = blockIdx.z;
    const int r0 = blockIdx.y * 64, c0 = blockIdx.x * 64;
    const float* src = in + (size_t)e * R * C;
    __hip_bfloat16* dst = out + (size_t)e * R * C;
    const int j = threadIdx.x & 63;
    const int i0 = threadIdx.x >> 6;
#pragma unroll
    for (int ii = 0; ii < 64; ii += 4) {
        int r = i0 + ii;
        tile[r][j] = src[(size_t)(r0 + r) * C + c0 + j];
    }
    __syncthreads();
#pragma unroll
    for (int ii = 0; ii < 64; ii += 4) {
        int c = i0 + ii;
        dst[(size_t)(c0 + c) * R + r0 + j] = __float2bfloat16(tile[j][c]);
    }
}

// ---------------- Expert GEMM (m97 structure: 128x128 tile, BK=64, 4 waves) ----------------
// MODE 1: h = relu(x_gathered @ W1^T' + b1), bf16 out.   A=[T][D] gathered, B=[E][H][D]
// MODE 2: oute = h @ W2^T' + b2, f32 out.                A=[E][CAP_PAD][H], B=[E][D][H]
template <int MODE>
__global__ __launch_bounds__(256) void ffn_gemm(
    const __hip_bfloat16* __restrict__ Abase,
    const __hip_bfloat16* __restrict__ Bt,
    const float* __restrict__ bias,
    const int* __restrict__ routed,
    const int* __restrict__ nkept,
    __hip_bfloat16* __restrict__ Hout,
    float* __restrict__ Oout)
{
    constexpr int KD = (MODE == 1) ? D_DIM : H_DIM;
    constexpr int ND = (MODE == 1) ? H_DIM : D_DIM;
    const int e = blockIdx.z;
    const int m0 = blockIdx.y * 128;
    const int n0 = blockIdx.x * 128;
    if (m0 >= nkept[e]) return;   // uniform per block

    __shared__ __hip_bfloat16 Al[128 * 64];
    __shared__ __hip_bfloat16 Bl[128 * 64];

    const int tid  = threadIdx.x;
    const int lane = tid & 63;
    const int w    = tid >> 6;
    const int srow = tid >> 3;          // 0..31
    const int skc  = (tid & 7) * 8;     // k element offset within BK

    const __hip_bfloat16* ag[4];
    const __hip_bfloat16* bg[4];
#pragma unroll
    for (int ii = 0; ii < 4; ++ii) {
        int m = m0 + srow + ii * 32;
        size_t arow = (MODE == 1) ? (size_t)routed[e * CAP_PAD + m]
                                  : ((size_t)e * CAP_PAD + m);
        ag[ii] = Abase + arow * KD + skc;
        int n = n0 + srow + ii * 32;
        bg[ii] = Bt + ((size_t)e * ND + n) * KD + skc;
    }

    f32x4 acc[4][4] = {};

    const int wm = (w >> 1) * 64;
    const int wn = (w & 1) * 64;
    const int fr = lane & 15;
    const int fq = lane >> 4;

    char* AlB = (char*)Al + w * 1024;   // wave-uniform LDS base; HW adds lane*16
    char* BlB = (char*)Bl + w * 1024;

    for (int k0 = 0; k0 < KD; k0 += 64) {
#pragma unroll
        for (int ii = 0; ii < 4; ++ii)
            __builtin_amdgcn_global_load_lds((gas_ptr)(ag[ii] + k0),
                                             (las_ptr)(AlB + ii * 4096), 16, 0, 0);
#pragma unroll
        for (int ii = 0; ii < 4; ++ii)
            __builtin_amdgcn_global_load_lds((gas_ptr)(bg[ii] + k0),
                                             (las_ptr)(BlB + ii * 4096), 16, 0, 0);
        __syncthreads();
#pragma unroll
        for (int kk = 0; kk < 2; ++kk) {
            short8 af[4], bf8[4];
#pragma unroll
            for (int i = 0; i < 4; ++i)
                af[i] = *(const short8*)(Al + (wm + i * 16 + fr) * 64 + kk * 32 + fq * 8);
#pragma unroll
            for (int i = 0; i < 4; ++i)
                bf8[i] = *(const short8*)(Bl + (wn + i * 16 + fr) * 64 + kk * 32 + fq * 8);
#pragma unroll
            for (int mi = 0; mi < 4; ++mi)
#pragma unroll
                for (int ni = 0; ni < 4; ++ni)
                    acc[mi][ni] = __builtin_amdgcn_mfma_f32_16x16x32_bf16(
                        af[mi], bf8[ni], acc[mi][ni], 0, 0, 0);
        }
        __syncthreads();
    }

#pragma unroll
    for (int ni = 0; ni < 4; ++ni) {
        int nc = n0 + wn + ni * 16 + fr;
        float bv = bias[e * ND + nc];
#pragma unroll
        for (int mi = 0; mi < 4; ++mi) {
            int mr = m0 + wm + mi * 16 + fq * 4;
#pragma unroll
            for (int r = 0; r < 4; ++r) {
                float v = acc[mi][ni][r] + bv;
                if (MODE == 1) {
                    v = fmaxf(v, 0.f);
                    Hout[((size_t)e * CAP_PAD + mr + r) * H_DIM + nc] = __float2bfloat16(v);
                } else {
                    Oout[((size_t)e * CAP_PAD + mr + r) * D_DIM + nc] = v;
                }
            }
        }
    }
}

// ---------------- Final gather: out[t] = sum_j gate_j * oute[inv_j] ----------------
__global__ void combine_kernel(const float* __restrict__ oute,
                               const int* __restrict__ inv,
                               const float* __restrict__ tok_g,
                               float* __restrict__ out)
{
    const int t = blockIdx.x;
    const int d = threadIdx.x * 4;
    const int i0 = inv[2 * t], i1 = inv[2 * t + 1];
    float4 r = make_float4(0.f, 0.f, 0.f, 0.f);
    if (i0 >= 0) {
        const float g = tok_g[2 * t];
        float4 v = *(const float4*)(oute + (size_t)i0 * D_DIM + d);
        r.x = g * v.x; r.y = g * v.y; r.z = g * v.z; r.w = g * v.w;
    }
    if (i1 >= 0) {
        const float g = tok_g[2 * t + 1];
        float4 v = *(const float4*)(oute + (size_t)i1 * D_DIM + d);
        r.x = fmaf(g, v.x, r.x); r.y = fmaf(g, v.y, r.y);
        r.z = fmaf(g, v.z, r.z); r.w = fmaf(g, v.w, r.w);
    }
    *(float4*)(out + (size_t)t * D_DIM + d) = r;
}

extern "C" void kernel_launch(void* const* d_in, const int* in_sizes, int n_in,
                              void* d_out, int out_size, void* d_ws, size_t ws_size,
                              hipStream_t stream)
{
    const float* x  = (const float*)d_in[0];
    const float* nz = (const float*)d_in[1];
    const float* Wr = (const float*)d_in[2];
    const float* br = (const float*)d_in[3];
    const float* Wn = (const float*)d_in[4];
    const float* bn = (const float*)d_in[5];
    const float* W1 = (const float*)d_in[6];
    const float* b1 = (const float*)d_in[7];
    const float* W2 = (const float*)d_in[8];
    const float* b2 = (const float*)d_in[9];
    float* out = (float*)d_out;
    char* ws = (char*)d_ws;

    // Workspace layout (~360 MiB total)
    size_t o_xb   = 0;
    size_t o_w1t  = o_xb   + (size_t)T_TOK * D_DIM * 2;
    size_t o_w2t  = o_w1t  + (size_t)E_NUM * H_DIM * D_DIM * 2;
    size_t o_h    = o_w2t  + (size_t)E_NUM * D_DIM * H_DIM * 2;
    size_t o_oute = o_h    + (size_t)E_NUM * CAP_PAD * H_DIM * 2;
    size_t o_rt   = o_oute + (size_t)E_NUM * CAP_PAD * D_DIM * 4;
    size_t o_te   = o_rt   + (size_t)E_NUM * CAP_PAD * 4;
    size_t o_tg   = o_te   + (size_t)T_TOK * 2 * 4;
    size_t o_inv  = o_tg   + (size_t)T_TOK * 2 * 4;
    size_t o_nk   = o_inv  + (size_t)T_TOK * 2 * 4;

    __hip_bfloat16* xb   = (__hip_bfloat16*)(ws + o_xb);
    __hip_bfloat16* w1t  = (__hip_bfloat16*)(ws + o_w1t);
    __hip_bfloat16* w2t  = (__hip_bfloat16*)(ws + o_w2t);
    __hip_bfloat16* hbuf = (__hip_bfloat16*)(ws + o_h);
    float*          oute = (float*)(ws + o_oute);
    int*            rt   = (int*)(ws + o_rt);
    int*            te   = (int*)(ws + o_te);
    float*          tg   = (float*)(ws + o_tg);
    int*            inv  = (int*)(ws + o_inv);
    int*            nk   = (int*)(ws + o_nk);

    hipMemsetAsync(inv, 0xFF, (size_t)T_TOK * 2 * 4, stream);   // inv = -1

    router_kernel<<<T_TOK / 4, 256, 0, stream>>>(x, nz, Wr, br, Wn, bn, xb, te, tg);
    scan_kernel<<<1, 512, 0, stream>>>(te, tg, rt, inv, nk, out + (size_t)T_TOK * D_DIM);
    transpose_kernel<<<dim3(H_DIM / 64, D_DIM / 64, E_NUM), 256, 0, stream>>>(W1, w1t, D_DIM, H_DIM);
    transpose_kernel<<<dim3(D_DIM / 64, H_DIM / 64, E_NUM), 256, 0, stream>>>(W2, w2t, H_DIM, D_DIM);
    ffn_gemm<1><<<dim3(H_DIM / 128, MT, E_NUM), 256, 0, stream>>>(xb, w1t, b1, rt, nk, hbuf, nullptr);
    ffn_gemm<2><<<dim3(D_DIM / 128, MT, E_NUM), 256, 0, stream>>>(hbuf, w2t, b2, rt, nk, nullptr, oute);
    combine_kernel<<<T_TOK, 256, 0, stream>>>(oute, inv, tg, out);
}

// Round 2
// 743.323 us; speedup vs baseline: 1.0866x; 1.0866x over previous
//
#include <hip/hip_runtime.h>
#include <hip/hip_bf16.h>

#define D_DIM 1024
#define H_DIM 4096
#define E_NUM 8
#define T_TOK 8192
#define CAPN 2252
#define CAP_PAD 2304   // 9 * 256
#define MT 9

typedef __attribute__((ext_vector_type(8))) short short8;
typedef __attribute__((ext_vector_type(4))) float f32x4;
typedef const __attribute__((address_space(1))) void* gas_ptr;
typedef __attribute__((address_space(3))) void* las_ptr;

__device__ __forceinline__ unsigned short f2bf(float f) {
    __hip_bfloat16 h = __float2bfloat16(f);
    return __builtin_bit_cast(unsigned short, h);
}

// ---------------- Router: logits, noisy top-2, gates; fuses x -> bf16 ----------------
__global__ void router_kernel(const float* __restrict__ x,
                              const float* __restrict__ noise,
                              const float* __restrict__ Wr,
                              const float* __restrict__ br,
                              const float* __restrict__ Wn,
                              const float* __restrict__ bn,
                              __hip_bfloat16* __restrict__ xb,
                              int* __restrict__ tok_e,
                              float* __restrict__ tok_g)
{
    const int l = threadIdx.x & 63;
    const int w = threadIdx.x >> 6;
    const int t = blockIdx.x * 4 + w;
    const float* xr = x + (size_t)t * D_DIM;

    float ar[8] = {0,0,0,0,0,0,0,0};
    float an[8] = {0,0,0,0,0,0,0,0};
#pragma unroll
    for (int i = 0; i < 4; ++i) {
        int d = i * 256 + l * 4;
        float4 xv = *(const float4*)(xr + d);
        ushort4 xq;
        xq.x = f2bf(xv.x); xq.y = f2bf(xv.y); xq.z = f2bf(xv.z); xq.w = f2bf(xv.w);
        *(ushort4*)(xb + (size_t)t * D_DIM + d) = xq;
        float xs[4] = {xv.x, xv.y, xv.z, xv.w};
#pragma unroll
        for (int j = 0; j < 4; ++j) {
            const float* wrp = Wr + (size_t)(d + j) * 8;
            float4 wa = *(const float4*)wrp;
            float4 wb = *(const float4*)(wrp + 4);
            ar[0] = fmaf(xs[j], wa.x, ar[0]); ar[1] = fmaf(xs[j], wa.y, ar[1]);
            ar[2] = fmaf(xs[j], wa.z, ar[2]); ar[3] = fmaf(xs[j], wa.w, ar[3]);
            ar[4] = fmaf(xs[j], wb.x, ar[4]); ar[5] = fmaf(xs[j], wb.y, ar[5]);
            ar[6] = fmaf(xs[j], wb.z, ar[6]); ar[7] = fmaf(xs[j], wb.w, ar[7]);
            const float* wnp = Wn + (size_t)(d + j) * 8;
            float4 na = *(const float4*)wnp;
            float4 nb = *(const float4*)(wnp + 4);
            an[0] = fmaf(xs[j], na.x, an[0]); an[1] = fmaf(xs[j], na.y, an[1]);
            an[2] = fmaf(xs[j], na.z, an[2]); an[3] = fmaf(xs[j], na.w, an[3]);
            an[4] = fmaf(xs[j], nb.x, an[4]); an[5] = fmaf(xs[j], nb.y, an[5]);
            an[6] = fmaf(xs[j], nb.z, an[6]); an[7] = fmaf(xs[j], nb.w, an[7]);
        }
    }
#pragma unroll
    for (int e = 0; e < 8; ++e) {
#pragma unroll
        for (int s = 32; s > 0; s >>= 1) {
            ar[e] += __shfl_xor(ar[e], s, 64);
            an[e] += __shfl_xor(an[e], s, 64);
        }
    }
    if (l == 0) {
        float nv[8];
#pragma unroll
        for (int e = 0; e < 8; ++e) {
            float z = an[e] + bn[e];
            float sp = fmaxf(z, 0.f) + log1pf(expf(-fabsf(z)));   // softplus, stable
            nv[e] = ar[e] + br[e] + noise[(size_t)t * 8 + e] * sp;
        }
        int e0 = 0; float v0 = nv[0];
#pragma unroll
        for (int e = 1; e < 8; ++e) if (nv[e] > v0) { v0 = nv[e]; e0 = e; }  // ties -> lower idx
        int e1 = -1; float v1 = -3.4e38f;
#pragma unroll
        for (int e = 0; e < 8; ++e) if (e != e0 && nv[e] > v1) { v1 = nv[e]; e1 = e; }
        float ex = expf(v1 - v0);          // v1 <= v0, no overflow
        float p0 = 1.f / (1.f + ex);
        float p1 = ex * p0;
        tok_e[2 * t]     = e0; tok_e[2 * t + 1] = e1;
        tok_g[2 * t]     = p0; tok_g[2 * t + 1] = p1;
    }
}

// ---------- Capacity scan: wave e compacts its tokens in order; lb_loss sums ----------
__global__ void scan_kernel(const int* __restrict__ tok_e,
                            const float* __restrict__ tok_g,
                            int* __restrict__ routed,
                            int* __restrict__ inv,
                            int* __restrict__ nkept,
                            float* __restrict__ lb_out)
{
    const int e = threadIdx.x >> 6;
    const int l = threadIdx.x & 63;
    __shared__ float s_g[E_NUM];
    __shared__ int   s_c[E_NUM];

    int run = 0;
    float gsum = 0.f;
    for (int c = 0; c < T_TOK / 64; ++c) {
        int t = c * 64 + l;
        int e0 = tok_e[2 * t];
        int e1 = tok_e[2 * t + 1];
        int j = (e0 == e) ? 0 : ((e1 == e) ? 1 : -1);
        bool sel = (j >= 0);
        unsigned long long m = __ballot(sel);
        if (sel) {
            int pos = run + __popcll(m & ((1ull << l) - 1ull));
            if (pos < CAPN) {
                routed[e * CAP_PAD + pos] = t;
                inv[2 * t + j] = e * CAP_PAD + pos;
            }
            gsum += tok_g[2 * t + j];     // pre-capacity, matches reference lb
        }
        run += __popcll(m);
    }
#pragma unroll
    for (int s = 32; s > 0; s >>= 1) gsum += __shfl_xor(gsum, s, 64);
    int nk = min(run, CAPN);
    for (int s = nk + l; s < CAP_PAD; s += 64) routed[e * CAP_PAD + s] = 0;  // safe pad
    if (l == 0) { nkept[e] = nk; s_g[e] = gsum; s_c[e] = run; }
    __syncthreads();
    if (threadIdx.x == 0) {
        float lb = 0.f;
        for (int ee = 0; ee < E_NUM; ++ee)
            lb += (s_g[ee] / (float)T_TOK) * ((float)s_c[ee] / (float)T_TOK);
        lb_out[0] = lb * (float)E_NUM;
    }
}

// -------- Transpose + f32->bf16: in [E][R][C] f32  ->  out [E][C][R] bf16 --------
__global__ void transpose_kernel(const float* __restrict__ in,
                                 __hip_bfloat16* __restrict__ out,
                                 int R, int C)
{
    __shared__ float tile[64][65];
    const int e = blockIdx.z;
    const int r0 = blockIdx.y * 64, c0 = blockIdx.x * 64;
    const float* src = in + (size_t)e * R * C;
    __hip_bfloat16* dst = out + (size_t)e * R * C;
    const int j = threadIdx.x & 63;
    const int i0 = threadIdx.x >> 6;
#pragma unroll
    for (int ii = 0; ii < 64; ii += 4) {
        int r = i0 + ii;
        tile[r][j] = src[(size_t)(r0 + r) * C + c0 + j];
    }
    __syncthreads();
#pragma unroll
    for (int ii = 0; ii < 64; ii += 4) {
        int c = i0 + ii;
        dst[(size_t)(c0 + c) * R + r0 + j] = __float2bfloat16(tile[j][c]);
    }
}

// ---------------- Expert GEMM: 256x256 tile, BK=32, 8 waves, 3-stage pipeline -------------
// LDS per stage: A 256x32 bf16 (16KB) + B 256x32 bf16 (16KB) = 32KB; 3 stages = 96KB.
// BK=32 -> 64B LDS rows -> fragment ds_read_b128 is bank-conflict-free with linear layout.
// Counted vmcnt(4): prefetch runs 2 K-tiles ahead into buffer (kt+2)%3 (last read at kt-1,
// so writes can never race reads); at each K-tile boundary vmcnt(4) leaves only the 4
// newest loads (K-tile kt+2) in flight => K-tile kt+1 is guaranteed resident.
// MODE 1: h = relu(gather(x) @ W1t + b1) -> bf16.  MODE 2: partial[s] = h @ W2t -> f32.
template <int MODE>
__global__ __launch_bounds__(512, 2) void ffn_gemm(
    const ushort* __restrict__ A, int lda,
    const ushort* __restrict__ Bt, int ldb,
    const float* __restrict__ bias,
    const int* __restrict__ routed,
    const int* __restrict__ nkept,
    ushort* __restrict__ outH,
    float*  __restrict__ outP,
    int sshift, int nkt)
{
    constexpr int ND = (MODE == 1) ? H_DIM : D_DIM;
    __shared__ ushort lds[49152];   // 96 KiB

    // XCD-aware swizzle (total blocks always % 8 == 0 here)
    unsigned total = gridDim.x * gridDim.y * gridDim.z;
    unsigned flat  = blockIdx.x + gridDim.x * (blockIdx.y + gridDim.y * blockIdx.z);
    unsigned sw    = (flat & 7) * (total >> 3) + (flat >> 3);
    unsigned bn    = sw % gridDim.x;
    unsigned t1    = sw / gridDim.x;
    unsigned bm    = t1 % gridDim.y;
    unsigned bz    = t1 / gridDim.y;

    const int e  = (int)(bz >> sshift);
    const int sp = (int)(bz & ((1u << sshift) - 1u));
    const int m0 = (int)bm * 256, n0 = (int)bn * 256;
    if (m0 >= nkept[e]) return;
    const int kbase = sp * (nkt << 5);

    const int tid  = threadIdx.x;
    const int lane = tid & 63;
    const int w    = tid >> 6;
    const int rloc = tid >> 2;           // 0..127 row within half-tile
    const int kc   = (tid & 3) << 3;     // k element offset 0,8,16,24
    const int wbyte = w << 10;           // wave-uniform LDS sub-base

    const ushort* ga[2];
    const ushort* gb[2];
#pragma unroll
    for (int u = 0; u < 2; ++u) {
        int mrow = m0 + u * 128 + rloc;
        long arow = (MODE == 1) ? (long)routed[e * CAP_PAD + mrow]
                                : (long)(e * CAP_PAD + mrow);
        ga[u] = A + arow * (long)lda + kbase + kc;
        int nrow = n0 + u * 128 + rloc;
        gb[u] = Bt + ((long)e * ND + nrow) * (long)ldb + kbase + kc;
    }

    auto issue = [&](const ushort* g, int ldsbyte) {
        __builtin_amdgcn_global_load_lds((gas_ptr)g, (las_ptr)((char*)lds + ldsbyte), 16, 0, 0);
    };

    // Prologue: stage K-tiles 0 (stage 0) and 1 (stage 1)
    issue(ga[0],      0     + wbyte);
    issue(ga[1],      8192  + wbyte);
    issue(gb[0],      16384 + wbyte);
    issue(gb[1],      24576 + wbyte);
    issue(ga[0] + 32, 32768 + 0     + wbyte);
    issue(ga[1] + 32, 32768 + 8192  + wbyte);
    issue(gb[0] + 32, 32768 + 16384 + wbyte);
    issue(gb[1] + 32, 32768 + 24576 + wbyte);
    asm volatile("s_waitcnt vmcnt(4)" ::: "memory");   // K-tile 0 resident
    __builtin_amdgcn_s_barrier();

    f32x4 acc[8][4] = {};
    const int wm = (w >> 2) * 128;
    const int wn = (w & 3) * 64;
    const int fr = lane & 15;
    const int fq = lane >> 4;

    int rdS = 0;          // short-index of read stage
    int wrB = 65536;      // byte offset of write stage ((kt+2)%3)

    for (int kt = 0; kt < nkt; ++kt) {
        const int ktp = min(kt + 2, nkt - 1) << 5;  // clamped prefetch (keeps vmcnt invariant)
        const ushort* Ard = lds + rdS;
        const ushort* Brd = lds + rdS + 8192;

        short8 af[4], bfr[4];
        // ---- phase 0: A rows 0-63 of wave's 128, all B ----
#pragma unroll
        for (int i = 0; i < 4; ++i)
            af[i] = *(const short8*)(Ard + (wm + i * 16 + fr) * 32 + fq * 8);
#pragma unroll
        for (int j = 0; j < 4; ++j)
            bfr[j] = *(const short8*)(Brd + (wn + j * 16 + fr) * 32 + fq * 8);
        issue(ga[0] + ktp, wrB + 0    + wbyte);
        issue(ga[1] + ktp, wrB + 8192 + wbyte);
        __builtin_amdgcn_s_barrier();
        __builtin_amdgcn_s_setprio(1);
#pragma unroll
        for (int i = 0; i < 4; ++i)
#pragma unroll
            for (int j = 0; j < 4; ++j)
                acc[i][j] = __builtin_amdgcn_mfma_f32_16x16x32_bf16(af[i], bfr[j], acc[i][j], 0, 0, 0);
        __builtin_amdgcn_s_setprio(0);
        __builtin_amdgcn_s_barrier();

        // ---- phase 1: A rows 64-127 ----
#pragma unroll
        for (int i = 0; i < 4; ++i)
            af[i] = *(const short8*)(Ard + (wm + 64 + i * 16 + fr) * 32 + fq * 8);
        issue(gb[0] + ktp, wrB + 16384 + wbyte);
        issue(gb[1] + ktp, wrB + 24576 + wbyte);
        __builtin_amdgcn_s_barrier();
        __builtin_amdgcn_s_setprio(1);
#pragma unroll
        for (int i = 0; i < 4; ++i)
#pragma unroll
            for (int j = 0; j < 4; ++j)
                acc[4 + i][j] = __builtin_amdgcn_mfma_f32_16x16x32_bf16(af[i], bfr[j], acc[4 + i][j], 0, 0, 0);
        __builtin_amdgcn_s_setprio(0);
        asm volatile("s_waitcnt vmcnt(4)" ::: "memory");   // K-tile kt+1 resident
        __builtin_amdgcn_s_barrier();

        rdS = (rdS == 32768) ? 0 : rdS + 16384;
        wrB = (wrB == 65536) ? 0 : wrB + 32768;
    }

    // ---- epilogue ----
#pragma unroll
    for (int j = 0; j < 4; ++j) {
        int nc = n0 + wn + j * 16 + fr;
        float bv = (MODE == 1) ? bias[e * ND + nc] : 0.f;
#pragma unroll
        for (int i = 0; i < 8; ++i) {
            int mr = m0 + wm + i * 16 + (fq << 2);
#pragma unroll
            for (int r = 0; r < 4; ++r) {
                float v = acc[i][j][r] + bv;
                if (MODE == 1) {
                    v = fmaxf(v, 0.f);
                    outH[((size_t)e * CAP_PAD + mr + r) * H_DIM + nc] = f2bf(v);
                } else {
                    outP[((size_t)(sp * E_NUM + e) * CAP_PAD + mr + r) * D_DIM + nc] = v;
                }
            }
        }
    }
}

// -------- Final combine: out[t] = sum_j gate_j * (sum_s part[s][inv_j] + b2[e_j]) --------
__global__ void combine_kernel(const float* __restrict__ part,
                               const int* __restrict__ inv,
                               const float* __restrict__ tok_g,
                               const float* __restrict__ b2,
                               int S,
                               float* __restrict__ out)
{
    const int t = blockIdx.x;
    const int d = threadIdx.x * 4;
    float4 r = make_float4(0.f, 0.f, 0.f, 0.f);
#pragma unroll
    for (int j = 0; j < 2; ++j) {
        int i = inv[2 * t + j];
        if (i >= 0) {
            float g = tok_g[2 * t + j];
            int e = i / CAP_PAD;
            float4 a = *(const float4*)(b2 + (size_t)e * D_DIM + d);
            for (int s = 0; s < S; ++s) {
                float4 p = *(const float4*)(part + ((size_t)s * E_NUM * CAP_PAD + i) * D_DIM + d);
                a.x += p.x; a.y += p.y; a.z += p.z; a.w += p.w;
            }
            r.x = fmaf(g, a.x, r.x); r.y = fmaf(g, a.y, r.y);
            r.z = fmaf(g, a.z, r.z); r.w = fmaf(g, a.w, r.w);
        }
    }
    *(float4*)(out + (size_t)t * D_DIM + d) = r;
}

extern "C" void kernel_launch(void* const* d_in, const int* in_sizes, int n_in,
                              void* d_out, int out_size, void* d_ws, size_t ws_size,
                              hipStream_t stream)
{
    const float* x  = (const float*)d_in[0];
    const float* nz = (const float*)d_in[1];
    const float* Wr = (const float*)d_in[2];
    const float* br = (const float*)d_in[3];
    const float* Wn = (const float*)d_in[4];
    const float* bn = (const float*)d_in[5];
    const float* W1 = (const float*)d_in[6];
    const float* b1 = (const float*)d_in[7];
    const float* W2 = (const float*)d_in[8];
    const float* b2 = (const float*)d_in[9];
    float* out = (float*)d_out;
    char* ws = (char*)d_ws;

    // Workspace layout:
    //   [w2t 64MB][h 144MB][small 1MB][dyn: phase1 = xb(16MB)+w1t(64MB) | phase2 = partials]
    const size_t sz_w2t = (size_t)E_NUM * D_DIM * H_DIM * 2;          // 67,108,864
    const size_t sz_h   = (size_t)E_NUM * CAP_PAD * H_DIM * 2;        // 150,994,944
    const size_t o_w2t  = 0;
    const size_t o_h    = o_w2t + sz_w2t;
    const size_t o_sm   = o_h + sz_h;
    const size_t o_dyn  = o_sm + (1u << 20);
    const size_t sz_xb  = (size_t)T_TOK * D_DIM * 2;                  // 16,777,216
    const size_t sz_w1t = (size_t)E_NUM * D_DIM * H_DIM * 2;          // 67,108,864
    const size_t sz_p1  = sz_xb + sz_w1t;                             // 83,886,080
    const size_t sz_part1 = (size_t)E_NUM * CAP_PAD * D_DIM * 4;      // 75,497,472

    int sshift = 2;
    while (sshift > 0) {
        size_t need = o_dyn + ((sz_part1 << sshift) > sz_p1 ? (sz_part1 << sshift) : sz_p1);
        if (need <= ws_size) break;
        --sshift;
    }
    const int S = 1 << sshift;

    ushort* w2t  = (ushort*)(ws + o_w2t);
    ushort* hbuf = (ushort*)(ws + o_h);
    int*    rt   = (int*)(ws + o_sm);
    int*    te   = (int*)(ws + o_sm + 131072);
    float*  tg   = (float*)(ws + o_sm + 262144);
    int*    inv  = (int*)(ws + o_sm + 393216);
    int*    nk   = (int*)(ws + o_sm + 524288);
    ushort* xb   = (ushort*)(ws + o_dyn);
    ushort* w1t  = (ushort*)(ws + o_dyn + sz_xb);
    float*  part = (float*)(ws + o_dyn);   // overlays xb/w1t (dead after GEMM1)

    hipMemsetAsync(inv, 0xFF, (size_t)T_TOK * 2 * 4, stream);   // inv = -1

    router_kernel<<<T_TOK / 4, 256, 0, stream>>>(x, nz, Wr, br, Wn, bn,
                                                 (__hip_bfloat16*)xb, te, tg);
    scan_kernel<<<1, 512, 0, stream>>>(te, tg, rt, inv, nk, out + (size_t)T_TOK * D_DIM);
    transpose_kernel<<<dim3(H_DIM / 64, D_DIM / 64, E_NUM), 256, 0, stream>>>(
        W1, (__hip_bfloat16*)w1t, D_DIM, H_DIM);
    transpose_kernel<<<dim3(D_DIM / 64, H_DIM / 64, E_NUM), 256, 0, stream>>>(
        W2, (__hip_bfloat16*)w2t, H_DIM, D_DIM);

    // GEMM1: [2304 x 1024] @ [1024 x 4096] per expert -> hbuf (bf16, relu+b1)
    ffn_gemm<1><<<dim3(H_DIM / 256, MT, E_NUM), 512, 0, stream>>>(
        xb, D_DIM, w1t, D_DIM, b1, rt, nk, hbuf, nullptr, 0, D_DIM / 32);

    // GEMM2: [2304 x 4096] @ [4096 x 1024] per expert, split-K=S -> f32 partials
    ffn_gemm<2><<<dim3(D_DIM / 256, MT, E_NUM << sshift), 512, 0, stream>>>(
        hbuf, H_DIM, w2t, H_DIM, nullptr, rt, nk, nullptr, part,
        sshift, (H_DIM / 32) >> sshift);

    combine_kernel<<<T_TOK, 256, 0, stream>>>(part, inv, tg, b2, S, out);
}